// Round 2
// baseline (268.438 us; speedup 1.0000x reference)
//
#include <hip/hip_runtime.h>
#include <math.h>

// B=16, C_in=32, C_out=32, H=256, W=256, K=16.
// S[b,i,v]   = (1/256) sum_w e^{-2pi i v w/256} * sum_h g[h] x[b,i,h,w],  g[h]=sum_{u<16} e^{-2pi i u h/256}
// blk[b,o,u,v] = sum_i S[b,i,u] * (Wr+iWi)[i,o,u,v]
// G[y,v]     = sum_u blk[u,v] e^{+2pi i u y/256}
// out[b,o,y,x] = (1/256)Re G[y,0] + (1/128) sum_{v=1..15} Re(G[y,v]) cos(2pi v x/256) - Im(G[y,v]) sin(2pi v x/256)
//
// Pipeline: k0 (twiddle tables) -> k1 (partial S) -> k2 (blk + G-coefs -> coef_g, 16 MB)
//           -> k3 (pure synthesis: no LDS, no barriers, scalar-loaded wave-uniform coefs).

#define TWO_PI_OVER_256 0.02454369260617026 /* 2*pi/256 */

// ---------------- K0: twiddle table, once (double precision) ----------------
__global__ __launch_bounds__(256) void k0_tables(float* __restrict__ tbl)
{
    const int t = threadIdx.x;
    const double a = TWO_PI_OVER_256 * (double)t;
    tbl[t]       = (float)cos(a);
    tbl[256 + t] = (float)sin(a);
}

// ---------------- K1: partial S over 64-row chunks ----------------
// grid = 512 (b*32+i) x 4 chunks = 2048 blocks.
// s_part layout: [bi][chunk][32] floats: [0..15]=Re S_partial, [16..31]=Im.
__global__ __launch_bounds__(256) void k1_partial(
    const float* __restrict__ x, const float* __restrict__ tbl,
    float* __restrict__ s_part)
{
    __shared__ float twc[256], tws[256];
    __shared__ float gre[64], gim[64];
    __shared__ float Pre[4][256], Pim[4][256];
    __shared__ float red_re[16][16], red_im[16][16];

    const int t = threadIdx.x;
    const int blk = blockIdx.x;
    const int bi = blk >> 2, chunk = blk & 3;
    const int y0 = chunk << 6;

    twc[t] = tbl[t];
    tws[t] = tbl[256 + t];
    __syncthreads();
    if (t < 64) {
        const int h = y0 + t;
        float gr = 0.f, gi = 0.f;
        #pragma unroll
        for (int u = 0; u < 16; ++u) {
            const int idx = (u * h) & 255;
            gr += twc[idx];
            gi -= tws[idx];
        }
        gre[t] = gr; gim[t] = gi;
    }
    __syncthreads();

    // Phase 1: partial P[w] = sum over 64 rows of g[h]*x[h,w]
    const float* img = x + (size_t)bi * 65536 + (size_t)y0 * 256;
    const int cg = t & 63, rg = t >> 6;
    float4 pr = {0.f,0.f,0.f,0.f}, pi = {0.f,0.f,0.f,0.f};
    #pragma unroll 4
    for (int k = 0; k < 16; ++k) {
        const int hl = rg + (k << 2);
        const float4 xv = *(const float4*)(img + (hl << 8) + (cg << 2));
        const float gr = gre[hl], gi = gim[hl];
        pr.x += gr * xv.x; pr.y += gr * xv.y; pr.z += gr * xv.z; pr.w += gr * xv.w;
        pi.x += gi * xv.x; pi.y += gi * xv.y; pi.z += gi * xv.z; pi.w += gi * xv.w;
    }
    *(float4*)&Pre[rg][cg << 2] = pr;
    *(float4*)&Pim[rg][cg << 2] = pi;
    __syncthreads();

    // Phase 2: S_partial[v] = (1/256) sum_w P[w] e^{-2pi i v w/256}
    {
        const int v = t >> 4, j = t & 15;
        float ar = 0.f, ai = 0.f;
        #pragma unroll
        for (int m = 0; m < 16; ++m) {
            const int w = j + (m << 4);
            const float prr = Pre[0][w] + Pre[1][w] + Pre[2][w] + Pre[3][w];
            const float pii = Pim[0][w] + Pim[1][w] + Pim[2][w] + Pim[3][w];
            const int idx = (v * w) & 255;
            const float c = twc[idx], s = tws[idx];
            ar += prr * c + pii * s;
            ai += pii * c - prr * s;
        }
        red_re[v][j] = ar; red_im[v][j] = ai;
    }
    __syncthreads();
    if (t < 16) {
        float ar = 0.f, ai = 0.f;
        #pragma unroll
        for (int j = 0; j < 16; ++j) { ar += red_re[t][j]; ai += red_im[t][j]; }
        float* sp = s_part + (size_t)bi * 128 + chunk * 32;
        sp[t]      = ar * (1.0f / 256.0f);
        sp[t + 16] = ai * (1.0f / 256.0f);
    }
}

// ---------------- K2: blk + G-coefs -> coef_g ----------------
// grid = 512 (b*32+o) x 4 row-chunks = 2048 blocks.
// coef_g layout: [bo][row 0..255][32]: [0..15]=cos-co (scaled), [16..31]=sin-co.
__global__ __launch_bounds__(256) void k2_coef(
    const float* __restrict__ wr, const float* __restrict__ wi,
    const float* __restrict__ s_part, const float* __restrict__ tbl,
    float* __restrict__ coef_g)
{
    __shared__ float Sre[32][16], Sim[32][16];
    __shared__ float Br[256], Bi[256];

    const int t = threadIdx.x;
    const int blk = blockIdx.x;
    const int bo = blk >> 2;
    const int y0 = (blk & 3) << 6;
    const int b = bo >> 5, o = bo & 31;

    // Load + sum the 4 S partials. 512 (i,u) pairs / 256 threads = 2 each.
    {
        const float* sb = s_part + (size_t)b * 4096;
        #pragma unroll
        for (int e = t; e < 512; e += 256) {
            const int i = e >> 4, u = e & 15;
            const float* p = sb + i * 128 + u;
            Sre[i][u] = p[0] + p[32] + p[64] + p[96];
            Sim[i][u] = p[16] + p[48] + p[80] + p[112];
        }
    }
    __syncthreads();

    // blk[u,v] = sum_i S[b,i,u] * W[i,o,u,v] (complex); t == u*16+v
    {
        const int u = t >> 4;
        float br = 0.f, bim = 0.f;
        const float* wrp = wr + o * 256 + t;   // [i][o][u][v]
        const float* wip = wi + o * 256 + t;
        #pragma unroll 8
        for (int i = 0; i < 32; ++i) {
            const float a_re = Sre[i][u], a_im = Sim[i][u];
            const float w_re = wrp[i * 8192], w_im = wip[i * 8192];
            br  += a_re * w_re - a_im * w_im;
            bim += a_re * w_im + a_im * w_re;
        }
        Br[t] = br; Bi[t] = bim;
    }
    __syncthreads();

    // G rows for this chunk: thread (v = t&15, slot = t>>4) handles rows slot*4+m.
    {
        const int v = t & 15, slot = t >> 4;
        float br[16], bim[16];
        #pragma unroll
        for (int u = 0; u < 16; ++u) { br[u] = Br[u * 16 + v]; bim[u] = Bi[u * 16 + v]; }
        const float scale = (v == 0) ? (1.0f / 256.0f) : (1.0f / 128.0f);
        float* cg = coef_g + (size_t)bo * 8192 + (size_t)y0 * 32;
        #pragma unroll
        for (int m = 0; m < 4; ++m) {
            const int r = slot * 4 + m;
            const int y = y0 + r;
            const float c1 = tbl[y], s1 = tbl[256 + y];   // e^{+2pi i y/256}
            float gr = br[0], gi = bim[0];
            float cc = 1.f, cs = 0.f;
            #pragma unroll
            for (int u = 1; u < 16; ++u) {
                const float nc = cc * c1 - cs * s1;
                const float ns = cc * s1 + cs * c1;
                cc = nc; cs = ns;
                gr += br[u] * cc - bim[u] * cs;
                gi += br[u] * cs + bim[u] * cc;
            }
            cg[r * 32 + v]      = gr * scale;
            cg[r * 32 + 16 + v] = (v == 0) ? 0.f : (-gi * scale);
        }
    }
}

// ---------------- K3: pure synthesis ----------------
// grid = 2048 blocks (bo x 4 chunks), 256 threads. No LDS, no barriers.
// Thread (c0 = t&63, rg = t>>6) -> columns {c0+64k}, rows rg*16 .. rg*16+15.
// rg is wave-uniform -> readfirstlane makes the coef row address scalar, so
// the 8 float4 coef reads per row become s_load (scalar cache, zero VGPR).
// cos/sin at x+64k are the base (cv,sv) rotated by i^v -> class sums:
//   out(c0+64k): a0=(P0+P2)+(P1+P3), a1=(P0-P2)+(Q1-Q3), a2=(P0+P2)-(P1+P3), a3=(P0-P2)-(Q1-Q3)
__global__ __launch_bounds__(256) void k3_synth(
    const float* __restrict__ coef_g, const float* __restrict__ tbl,
    float* __restrict__ out)
{
    const int t = threadIdx.x;
    const int blk = blockIdx.x;
    const int bo = blk >> 2;
    const int y0 = (blk & 3) << 6;
    const int c0 = t & 63;
    const int rg = __builtin_amdgcn_readfirstlane(t >> 6);

    float cv[16], sv[16];
    #pragma unroll
    for (int v = 0; v < 16; ++v) {
        const int idx = (v * c0) & 255;
        cv[v] = tbl[idx];
        sv[v] = tbl[256 + idx];
    }
    sv[0] = 0.f;

#define PTERM(ACC, C_, S_, vv) ACC += (C_) * cv[vv] + (S_) * sv[vv];
#define QTERM(ACC, C_, S_, vv) ACC += (S_) * cv[vv] - (C_) * sv[vv];

    const float* crow_base = coef_g + (size_t)bo * 8192 + (size_t)(y0 + rg * 16) * 32;
    float* op = out + (size_t)bo * 65536 + (size_t)(y0 + rg * 16) * 256 + c0;

    #pragma unroll 4
    for (int rr = 0; rr < 16; ++rr) {
        const float4* crow = (const float4*)(crow_base + rr * 32);
        const float4 pc0 = crow[0], pc1 = crow[1], pc2 = crow[2], pc3 = crow[3];
        const float4 ps0 = crow[4], ps1 = crow[5], ps2 = crow[6], ps3 = crow[7];
        float P0 = 0.f, P1 = 0.f, P2 = 0.f, P3 = 0.f, Q1 = 0.f, Q3 = 0.f;
        PTERM(P0, pc0.x, ps0.x, 0)
        PTERM(P1, pc0.y, ps0.y, 1)   QTERM(Q1, pc0.y, ps0.y, 1)
        PTERM(P2, pc0.z, ps0.z, 2)
        PTERM(P3, pc0.w, ps0.w, 3)   QTERM(Q3, pc0.w, ps0.w, 3)
        PTERM(P0, pc1.x, ps1.x, 4)
        PTERM(P1, pc1.y, ps1.y, 5)   QTERM(Q1, pc1.y, ps1.y, 5)
        PTERM(P2, pc1.z, ps1.z, 6)
        PTERM(P3, pc1.w, ps1.w, 7)   QTERM(Q3, pc1.w, ps1.w, 7)
        PTERM(P0, pc2.x, ps2.x, 8)
        PTERM(P1, pc2.y, ps2.y, 9)   QTERM(Q1, pc2.y, ps2.y, 9)
        PTERM(P2, pc2.z, ps2.z, 10)
        PTERM(P3, pc2.w, ps2.w, 11)  QTERM(Q3, pc2.w, ps2.w, 11)
        PTERM(P0, pc3.x, ps3.x, 12)
        PTERM(P1, pc3.y, ps3.y, 13)  QTERM(Q1, pc3.y, ps3.y, 13)
        PTERM(P2, pc3.z, ps3.z, 14)
        PTERM(P3, pc3.w, ps3.w, 15)  QTERM(Q3, pc3.w, ps3.w, 15)

        const float e02 = P0 + P2, o13 = P1 + P3;
        const float d02 = P0 - P2, dq  = Q1 - Q3;
        float* row = op + (rr << 8);
        row[0]   = e02 + o13;
        row[64]  = d02 + dq;
        row[128] = e02 - o13;
        row[192] = d02 - dq;
    }
#undef PTERM
#undef QTERM
}

extern "C" void kernel_launch(void* const* d_in, const int* in_sizes, int n_in,
                              void* d_out, int out_size, void* d_ws, size_t ws_size,
                              hipStream_t stream) {
    (void)in_sizes; (void)n_in; (void)out_size; (void)ws_size;
    const float* x  = (const float*)d_in[0];
    const float* wr = (const float*)d_in[1];
    const float* wi = (const float*)d_in[2];
    float* out    = (float*)d_out;
    float* s_part = (float*)d_ws;              // 65536 floats = 256 KB
    float* tbl    = s_part + 65536;            // 512 floats (cos | sin)
    float* coef_g = tbl + 512;                 // 512*256*32 floats = 16 MB

    k0_tables<<<1, 256, 0, stream>>>(tbl);
    k1_partial<<<2048, 256, 0, stream>>>(x, tbl, s_part);
    k2_coef<<<2048, 256, 0, stream>>>(wr, wi, s_part, tbl, coef_g);
    k3_synth<<<2048, 256, 0, stream>>>(coef_g, tbl, out);
}

// Round 4
// 248.986 us; speedup vs baseline: 1.0781x; 1.0781x over previous
//
#include <hip/hip_runtime.h>
#include <math.h>

// B=16, C_in=32, C_out=32, H=256, W=256, K=16.
// S[b,i,v]   = (1/256) sum_w e^{-2pi i v w/256} * sum_h g[h] x[b,i,h,w],  g[h]=sum_{u<16} e^{-2pi i u h/256}
// blk[b,o,u,v] = sum_i S[b,i,u] * (Wr+iWi)[i,o,u,v]
// G[y,v]     = sum_u blk[u,v] e^{+2pi i u y/256}
// out[b,o,y,x] = (1/256)Re G[y,0] + (1/128) sum_{v=1..15} Re(G[y,v]) cos(2pi v x/256) - Im(G[y,v]) sin(2pi v x/256)

#define TWO_PI_OVER_256 0.02454369260617026 /* 2*pi/256 */

// ---------------- K0: twiddle table, once (double precision) ----------------
__global__ __launch_bounds__(256) void k0_tables(float* __restrict__ tbl)
{
    const int t = threadIdx.x;
    const double a = TWO_PI_OVER_256 * (double)t;
    tbl[t]       = (float)cos(a);
    tbl[256 + t] = (float)sin(a);
}

// ---------------- K1: partial S over 64-row chunks ----------------
// grid = 512 (b*32+i) x 4 chunks = 2048 blocks.
// s_part layout: [bi][chunk][32] floats: [0..15]=Re S_partial, [16..31]=Im.
// Phase 2 uses a pre-reduced P array + in-register twiddle recurrence.
__global__ __launch_bounds__(256) void k1_partial(
    const float* __restrict__ x, const float* __restrict__ tbl,
    float* __restrict__ s_part)
{
    __shared__ float twc[256], tws[256];
    __shared__ float gre[64], gim[64];
    __shared__ float Pre[4][256], Pim[4][256];
    __shared__ float red_re[16][16], red_im[16][16];

    const int t = threadIdx.x;
    const int blk = blockIdx.x;
    const int bi = blk >> 2, chunk = blk & 3;
    const int y0 = chunk << 6;

    twc[t] = tbl[t];
    tws[t] = tbl[256 + t];
    __syncthreads();
    if (t < 64) {
        const int h = y0 + t;
        float gr = 0.f, gi = 0.f;
        #pragma unroll
        for (int u = 0; u < 16; ++u) {
            const int idx = (u * h) & 255;
            gr += twc[idx];
            gi -= tws[idx];
        }
        gre[t] = gr; gim[t] = gi;
    }
    __syncthreads();

    // Phase 1: partial P[w] = sum over 64 rows of g[h]*x[h,w]
    const float* img = x + (size_t)bi * 65536 + (size_t)y0 * 256;
    const int cg = t & 63, rg = t >> 6;
    float4 pr = {0.f,0.f,0.f,0.f}, pi = {0.f,0.f,0.f,0.f};
    #pragma unroll 4
    for (int k = 0; k < 16; ++k) {
        const int hl = rg + (k << 2);
        const float4 xv = *(const float4*)(img + (hl << 8) + (cg << 2));
        const float gr = gre[hl], gi = gim[hl];
        pr.x += gr * xv.x; pr.y += gr * xv.y; pr.z += gr * xv.z; pr.w += gr * xv.w;
        pi.x += gi * xv.x; pi.y += gi * xv.y; pi.z += gi * xv.z; pi.w += gi * xv.w;
    }
    *(float4*)&Pre[rg][cg << 2] = pr;
    *(float4*)&Pim[rg][cg << 2] = pi;
    __syncthreads();

    // Pre-reduce: fold the 4 row-group partials into Pre[0]/Pim[0].
    // Thread t owns column t; write-after-read on own slot only.
    {
        const float sr = Pre[0][t] + Pre[1][t] + Pre[2][t] + Pre[3][t];
        const float si = Pim[0][t] + Pim[1][t] + Pim[2][t] + Pim[3][t];
        Pre[0][t] = sr;
        Pim[0][t] = si;
    }
    __syncthreads();

    // Phase 2: S_partial[v] = (1/256) sum_w P[w] e^{-2pi i v w/256}
    // w = j + 16m; twiddle advanced by rotation e^{-2pi i 16v/256} per step.
    {
        const int v = t >> 4, j = t & 15;
        const int i0 = (v * j) & 255;
        float c = twc[i0], s = tws[i0];
        const int id = (v << 4) & 255;
        const float cd = twc[id], sd = tws[id];
        float ar = 0.f, ai = 0.f;
        #pragma unroll
        for (int m = 0; m < 16; ++m) {
            const int w = j + (m << 4);
            const float prr = Pre[0][w];
            const float pii = Pim[0][w];
            ar += prr * c + pii * s;
            ai += pii * c - prr * s;
            const float nc = c * cd - s * sd;
            const float ns = s * cd + c * sd;
            c = nc; s = ns;
        }
        red_re[v][j] = ar; red_im[v][j] = ai;
    }
    __syncthreads();
    if (t < 16) {
        const float4* rr4 = (const float4*)&red_re[t][0];
        const float4* ri4 = (const float4*)&red_im[t][0];
        float ar = 0.f, ai = 0.f;
        #pragma unroll
        for (int q = 0; q < 4; ++q) {
            const float4 a = rr4[q], b = ri4[q];
            ar += a.x + a.y + a.z + a.w;
            ai += b.x + b.y + b.z + b.w;
        }
        float* sp = s_part + (size_t)bi * 128 + chunk * 32;
        sp[t]      = ar * (1.0f / 256.0f);
        sp[t + 16] = ai * (1.0f / 256.0f);
    }
}

// ---------------- K23: blk + G-coefs + synthesis, fused ----------------
// grid = 512 (b*32+o) x 4 row-chunks = 2048 blocks, 64 rows each.
// blk stored transposed+padded (Bt[v*20+u], 80B rows, 16B-aligned, <=2-way banks)
// so the G-coef phase reads it as 8x ds_read_b128 instead of 32x b32.
// Synthesis: each thread covers 4 columns {c0+64k} x 16 rows; cos/sin at x+64k
// are the base (cv,sv) rotated by i^v -> class sums; nontemporal out stores.
__global__ __launch_bounds__(256) void k23_synth(
    const float* __restrict__ wr, const float* __restrict__ wi,
    const float* __restrict__ s_part, const float* __restrict__ tbl,
    float* __restrict__ out)
{
    __shared__ float twc[256], tws[256];
    __shared__ float Sre[32][16], Sim[32][16];
    __shared__ float Btr[16 * 20], Bti[16 * 20];
    __shared__ __align__(16) float coef[64][36];  // [row][0..15]=cos-co, [16..31]=sin-co; stride 36

    const int t = threadIdx.x;
    const int blk = blockIdx.x;
    const int bo = blk >> 2;
    const int y0 = (blk & 3) << 6;
    const int b = bo >> 5, o = bo & 31;

    twc[t] = tbl[t];
    tws[t] = tbl[256 + t];
    // Load + sum the 4 S partials. 512 (i,u) pairs / 256 threads = 2 each.
    {
        const float* sb = s_part + (size_t)b * 4096;
        #pragma unroll
        for (int e = t; e < 512; e += 256) {
            const int i = e >> 4, u = e & 15;
            const float* p = sb + i * 128 + u;
            Sre[i][u] = p[0] + p[32] + p[64] + p[96];
            Sim[i][u] = p[16] + p[48] + p[80] + p[112];
        }
    }
    __syncthreads();

    // blk[u,v] = sum_i S[b,i,u] * W[i,o,u,v] (complex); t == u*16+v
    {
        const int u = t >> 4, v = t & 15;
        float br = 0.f, bim = 0.f;
        const float* wrp = wr + o * 256 + t;   // [i][o][u][v]
        const float* wip = wi + o * 256 + t;
        #pragma unroll 8
        for (int i = 0; i < 32; ++i) {
            const float a_re = Sre[i][u], a_im = Sim[i][u];
            const float w_re = wrp[i * 8192], w_im = wip[i * 8192];
            br  += a_re * w_re - a_im * w_im;
            bim += a_re * w_im + a_im * w_re;
        }
        Btr[v * 20 + u] = br;
        Bti[v * 20 + u] = bim;
    }
    __syncthreads();

    // G rows for this chunk: thread (v = t&15, slot = t>>4) handles rows slot*4+m.
    {
        const int v = t & 15, slot = t >> 4;
        float br[16], bim[16];
        const float4* bpr = (const float4*)&Btr[v * 20];
        const float4* bpi = (const float4*)&Bti[v * 20];
        #pragma unroll
        for (int q = 0; q < 4; ++q) {
            const float4 r4 = bpr[q], i4 = bpi[q];
            br[q*4+0]  = r4.x; br[q*4+1]  = r4.y; br[q*4+2]  = r4.z; br[q*4+3]  = r4.w;
            bim[q*4+0] = i4.x; bim[q*4+1] = i4.y; bim[q*4+2] = i4.z; bim[q*4+3] = i4.w;
        }
        const float scale = (v == 0) ? (1.0f / 256.0f) : (1.0f / 128.0f);
        #pragma unroll
        for (int m = 0; m < 4; ++m) {
            const int r = slot * 4 + m;
            const int y = y0 + r;
            const float c1 = twc[y], s1 = tws[y];   // e^{+2pi i y/256}
            float gr = br[0], gi = bim[0];
            float cc = 1.f, cs = 0.f;
            #pragma unroll
            for (int u = 1; u < 16; ++u) {
                const float nc = cc * c1 - cs * s1;
                const float ns = cc * s1 + cs * c1;
                cc = nc; cs = ns;
                gr += br[u] * cc - bim[u] * cs;
                gi += br[u] * cs + bim[u] * cc;
            }
            coef[r][v]      = gr * scale;
            coef[r][16 + v] = (v == 0) ? 0.f : (-gi * scale);
        }
    }
    __syncthreads();

    // Synthesis: thread (c0 = t&63, rg = t>>6) -> columns {c0+64k}, rows rg*16..rg*16+15.
    const int c0 = t & 63, rg = t >> 6;
    float cv[16], sv[16];
    #pragma unroll
    for (int v = 0; v < 16; ++v) {
        const int idx = (v * c0) & 255;
        cv[v] = twc[idx];
        sv[v] = tws[idx];
    }
    sv[0] = 0.f;

#define PTERM(ACC, C_, S_, vv) ACC += (C_) * cv[vv] + (S_) * sv[vv];
#define QTERM(ACC, C_, S_, vv) ACC += (S_) * cv[vv] - (C_) * sv[vv];

    float* op = out + (size_t)bo * 65536 + (size_t)y0 * 256 + c0;
    #pragma unroll 2
    for (int rr = 0; rr < 16; ++rr) {
        const int r = (rg << 4) + rr;
        const float4* crow = (const float4*)&coef[r][0];
        const float4 pc0 = crow[0], pc1 = crow[1], pc2 = crow[2], pc3 = crow[3];
        const float4 ps0 = crow[4], ps1 = crow[5], ps2 = crow[6], ps3 = crow[7];
        float P0 = 0.f, P1 = 0.f, P2 = 0.f, P3 = 0.f, Q1 = 0.f, Q3 = 0.f;
        PTERM(P0, pc0.x, ps0.x, 0)
        PTERM(P1, pc0.y, ps0.y, 1)   QTERM(Q1, pc0.y, ps0.y, 1)
        PTERM(P2, pc0.z, ps0.z, 2)
        PTERM(P3, pc0.w, ps0.w, 3)   QTERM(Q3, pc0.w, ps0.w, 3)
        PTERM(P0, pc1.x, ps1.x, 4)
        PTERM(P1, pc1.y, ps1.y, 5)   QTERM(Q1, pc1.y, ps1.y, 5)
        PTERM(P2, pc1.z, ps1.z, 6)
        PTERM(P3, pc1.w, ps1.w, 7)   QTERM(Q3, pc1.w, ps1.w, 7)
        PTERM(P0, pc2.x, ps2.x, 8)
        PTERM(P1, pc2.y, ps2.y, 9)   QTERM(Q1, pc2.y, ps2.y, 9)
        PTERM(P2, pc2.z, ps2.z, 10)
        PTERM(P3, pc2.w, ps2.w, 11)  QTERM(Q3, pc2.w, ps2.w, 11)
        PTERM(P0, pc3.x, ps3.x, 12)
        PTERM(P1, pc3.y, ps3.y, 13)  QTERM(Q1, pc3.y, ps3.y, 13)
        PTERM(P2, pc3.z, ps3.z, 14)
        PTERM(P3, pc3.w, ps3.w, 15)  QTERM(Q3, pc3.w, ps3.w, 15)

        const float e02 = P0 + P2, o13 = P1 + P3;
        const float d02 = P0 - P2, dq  = Q1 - Q3;
        float* row = op + (r << 8);   // FIXED: r (= rg*16+rr), not rr — round 3's merge bug
        __builtin_nontemporal_store(e02 + o13, row);
        __builtin_nontemporal_store(d02 + dq,  row + 64);
        __builtin_nontemporal_store(e02 - o13, row + 128);
        __builtin_nontemporal_store(d02 - dq,  row + 192);
    }
#undef PTERM
#undef QTERM
}

extern "C" void kernel_launch(void* const* d_in, const int* in_sizes, int n_in,
                              void* d_out, int out_size, void* d_ws, size_t ws_size,
                              hipStream_t stream) {
    (void)in_sizes; (void)n_in; (void)out_size; (void)ws_size;
    const float* x  = (const float*)d_in[0];
    const float* wr = (const float*)d_in[1];
    const float* wi = (const float*)d_in[2];
    float* out    = (float*)d_out;
    float* s_part = (float*)d_ws;          // 65536 floats = 256 KB
    float* tbl    = s_part + 65536;        // 512 floats (cos | sin)

    k0_tables<<<1, 256, 0, stream>>>(tbl);
    k1_partial<<<2048, 256, 0, stream>>>(x, tbl, s_part);
    k23_synth<<<2048, 256, 0, stream>>>(wr, wi, s_part, tbl, out);
}